// Round 8
// baseline (2664.302 us; speedup 1.0000x reference)
//
#include <hip/hip_runtime.h>
#include <math.h>

#define S0 32
#define NRBF 16
#define NA 32
#define NB 16
#define MDIM 80            // NA + 3*NB
#define NELEM 118
#define CAP 96             // bucket capacity per center
#define NBIN 18            // m0 bins 0..17 (17 = "both channels zero")

__device__ inline unsigned short f2bf(float a) {
    unsigned u = __float_as_uint(a);
    return (unsigned short)((u + 0x7fffu + ((u >> 16) & 1u)) >> 16);
}
__device__ inline unsigned pack_bf2(float a, float b) {
    return (unsigned)f2bf(a) | ((unsigned)f2bf(b) << 16);
}
__device__ inline float bf2f(unsigned short u) {
    return __uint_as_float(((unsigned)u) << 16);
}

// ---------------- Kernel 0: weight transpose (fp32, for scalar-broadcast reads) ----------------
__global__ void k_prep(const float* __restrict__ Ws, const float* __restrict__ Wv,
                       float* __restrict__ WsT, float* __restrict__ WvT) {
    int t = blockIdx.x * 256 + threadIdx.x;
    if (t < NRBF * 48 * S0) {          // WsT[j][k][i] = Ws[i][j][k]
        int j = t / (48 * S0);
        int r = t - j * (48 * S0);
        int k = r / S0;
        int i = r - k * S0;
        WsT[t] = Ws[(i * NRBF + j) * 48 + k];
    }
    if (t < NB * S0) {                 // WvT[k][i] = Wv[i][k]
        int k = t / S0, i = t - k * S0;
        WvT[t] = Wv[i * NB + k];
    }
}

// ---------------- Kernel 1: node features (LDS-staged coalesced reads) ----------------
__global__ void __launch_bounds__(256)
k_node_feat(const float* __restrict__ elem_id,
            const float* __restrict__ charge,
            const float* __restrict__ emb,
            const float* __restrict__ Wfeat,
            float* __restrict__ node_feat, int n) {
    __shared__ float rows[64 * 121];
    __shared__ float WfL[11 * S0];
    int tid = threadIdx.x;
    int blockBase = blockIdx.x * 64;
    int nRows = n - blockBase; if (nRows > 64) nRows = 64;
    if (nRows <= 0) return;
    int totF = nRows * NELEM;
    const float* src = elem_id + (size_t)blockBase * NELEM;
    for (int t = tid; t < totF; t += 256) {
        int r = t / NELEM, c = t - r * NELEM;
        rows[r * 121 + c] = src[t];
    }
    for (int t = tid; t < 11 * S0; t += 256) WfL[t] = Wfeat[t];
    __syncthreads();
    if (tid >= nRows) return;
    int i = blockBase + tid;
    const float* myrow = rows + tid * 121;
    float best = -1e30f; int bi = 0;
    for (int c = 0; c < NELEM; ++c) {
        float v = myrow[c];
        if (v > best) { best = v; bi = c; }
    }
    float ns[11];
#pragma unroll
    for (int c = 0; c < 10; ++c) ns[c] = emb[bi * 10 + c];
    ns[10] = charge[i];
    float out[S0];
#pragma unroll
    for (int k = 0; k < S0; ++k) out[k] = 0.f;
#pragma unroll
    for (int c = 0; c < 11; ++c) {
        float f = ns[c];
#pragma unroll
        for (int k = 0; k < S0; ++k) out[k] = fmaf(f, WfL[c * S0 + k], out[k]);
    }
    float4* o = (float4*)(node_feat + (size_t)i * S0);
#pragma unroll
    for (int q = 0; q < S0 / 4; ++q)
        o[q] = make_float4(out[4 * q], out[4 * q + 1], out[4 * q + 2], out[4 * q + 3]);
}

// ---------------- Kernel 2: bucket fill + bin count ----------------
__global__ void k_fill2(const float* __restrict__ pos, const int* __restrict__ center_idx,
                        const int* __restrict__ edge_center, const int* __restrict__ edge_env,
                        int* __restrict__ cnt_int, int* __restrict__ bucket,
                        int* __restrict__ bine, int* __restrict__ bin_cnt, int nE) {
    int e = blockIdx.x * blockDim.x + threadIdx.x;
    if (e >= nE) return;
    int ec = edge_center[e];
    int en = edge_env[e];
    int gc = center_idx[ec];
    float px = pos[3 * (size_t)gc + 0] - pos[3 * (size_t)en + 0];
    float py = pos[3 * (size_t)gc + 1] - pos[3 * (size_t)en + 1];
    float pz = pos[3 * (size_t)gc + 2] - pos[3 * (size_t)en + 2];
    float d = sqrtf(px * px + py * py + pz * pz) + 1e-8f;
    const float inv_step = 3.4f;  // (NRBF+1)/5
    float u = d * inv_step;
    int m0 = (int)floorf(u);
    if (m0 > 17) m0 = 17;
    bine[e] = m0;
    atomicAdd(&bin_cnt[m0], 1);
    int slot = atomicAdd(&cnt_int[ec], 1);
    if (slot < CAP) bucket[(size_t)ec * CAP + slot] = e;
}

// ---------------- Kernel 3: padded prefix over 18 bins ----------------
__global__ void k_prefix(const int* __restrict__ bin_cnt, int* __restrict__ pad_base) {
    if (threadIdx.x == 0 && blockIdx.x == 0) {
        int acc = 0;
        for (int b = 0; b < NBIN; ++b) {
            pad_base[b] = acc;
            acc += ((bin_cnt[b] + 255) / 256) * 256;
        }
        pad_base[NBIN] = acc;
    }
}

// ---------------- Kernel 4: scatter edges into padded bin CSR ----------------
__global__ void k_scatter(const int* __restrict__ bine, const int* __restrict__ pad_base,
                          int* __restrict__ cursor, int* __restrict__ bin_edges, int nE) {
    int e = blockIdx.x * blockDim.x + threadIdx.x;
    if (e >= nE) return;
    int b = bine[e];
    int p = atomicAdd(&cursor[b], 1);
    bin_edges[pad_base[b] + p] = e;
}

// ---------------- Kernel 5: binned per-edge tensor product (wave-uniform weights) ----------------
__global__ void __launch_bounds__(256)
k_edges_b(const float* __restrict__ pos, const int* __restrict__ center_idx,
          const int* __restrict__ edge_center, const int* __restrict__ edge_env,
          const float* __restrict__ WsT,   // [j][k][i] fp32
          const float* __restrict__ WvT,   // [k][i] fp32
          const float* __restrict__ node_feat,
          const int* __restrict__ bin_edges, const int* __restrict__ pad_base,
          uint4* __restrict__ edge_m) {
    __shared__ int pbS[NBIN + 1];
    if (threadIdx.x <= NBIN) pbS[threadIdx.x] = pad_base[threadIdx.x];
    __syncthreads();
    int slotBase = blockIdx.x * 256;
    int total = pbS[NBIN];
    if (slotBase >= total) return;
    int b = 0;
    while (b < NBIN - 1 && slotBase >= pbS[b + 1]) ++b;   // block lies in ONE bin (padded)
    b = __builtin_amdgcn_readfirstlane(b);

    int slot = slotBase + threadIdx.x;
    int e = (slot < total) ? bin_edges[slot] : -1;
    bool valid = e >= 0;
    int ei = valid ? e : 0;

    int ec = edge_center[ei];
    int en = edge_env[ei];
    int gc = center_idx[ec];
    float px = pos[3 * (size_t)gc + 0] - pos[3 * (size_t)en + 0];
    float py = pos[3 * (size_t)gc + 1] - pos[3 * (size_t)en + 1];
    float pz = pos[3 * (size_t)gc + 2] - pos[3 * (size_t)en + 2];
    float d = sqrtf(px * px + py * py + pz * pz) + 1e-8f;

    const float inv_step = 3.4f;
    float u = d * inv_step;
    float f0 = u - (float)b;            // exact: b == floor(u) for b<=16
    float t0 = 0.5f * (float)M_PI * f0;
    float r0 = (b >= 1 && b <= 16) ? cosf(t0) : 0.f;   // channel j0 = b-1
    float r1 = (b <= 15) ? sinf(t0) : 0.f;             // channel j1 = b
    if (!valid) { r0 = 0.f; r1 = 0.f; }
    int j0 = b - 1; if (j0 < 0) j0 = 0; if (j0 > 15) j0 = 15;
    int j1 = b;     if (j1 > 15) j1 = 15;
    const float* w0 = WsT + j0 * (48 * S0);   // wave-uniform row pointers -> s_load
    const float* w1 = WsT + j1 * (48 * S0);

    float h[S0];
    {
        const float4* hp = (const float4*)(node_feat + (size_t)en * S0);
#pragma unroll
        for (int q = 0; q < S0 / 4; ++q) {
            float4 t = hp[q];
            h[4 * q + 0] = t.x; h[4 * q + 1] = t.y; h[4 * q + 2] = t.z; h[4 * q + 3] = t.w;
        }
    }

    float acc[48];
#pragma unroll 2
    for (int k = 0; k < 48; ++k) {
        float a0 = 0.f, a1 = 0.f;
        const float* w0k = w0 + k * S0;
        const float* w1k = w1 + k * S0;
#pragma unroll
        for (int i = 0; i < S0; ++i) {
            a0 = fmaf(h[i], w0k[i], a0);
            a1 = fmaf(h[i], w1k[i], a1);
        }
        acc[k] = fmaf(r0, a0, r1 * a1);
    }

    float hv[NB];
#pragma unroll 2
    for (int k = 0; k < NB; ++k) {
        float a = 0.f;
        const float* wk = WvT + k * S0;
#pragma unroll
        for (int i = 0; i < S0; ++i) a = fmaf(h[i], wk[i], a);
        hv[k] = a;
    }

    const float inv_s = 0.04419417382415922f;  // 1/sqrt(512)
    const float inv_v = 0.17677669529663687f;  // 1/sqrt(32)
    float m[MDIM];
#pragma unroll
    for (int k = 0; k < NA; ++k) {
        float s = acc[k] * inv_s;
        float sg = 1.f / (1.f + expf(-s));
        m[k] = s * sg;
    }
    float ys = 1.7320508075688772f / d;
    float Yx = ys * px, Yy = ys * py, Yz = ys * pz;
#pragma unroll
    for (int k = 0; k < NB; ++k) {
        float s = acc[NA + k] * inv_s;
        float g = 1.f / (1.f + expf(-s));
        float vv = hv[k] * inv_v * g;
        m[NA + 3 * k + 0] = vv * Yx;
        m[NA + 3 * k + 1] = vv * Yy;
        m[NA + 3 * k + 2] = vv * Yz;
    }

    if (valid) {
        uint4* dst = edge_m + (size_t)ei * 10;
#pragma unroll
        for (int q = 0; q < 10; ++q) {
            uint4 w;
            w.x = pack_bf2(m[8 * q + 0], m[8 * q + 1]);
            w.y = pack_bf2(m[8 * q + 2], m[8 * q + 3]);
            w.z = pack_bf2(m[8 * q + 4], m[8 * q + 5]);
            w.w = pack_bf2(m[8 * q + 6], m[8 * q + 7]);
            dst[q] = w;
        }
    }
}

// ---------------- Kernel 6: per-center reduce + finalize ----------------
__global__ void __launch_bounds__(128)
k_centers(const unsigned short* __restrict__ edge_m,
          const int* __restrict__ bucket, const int* __restrict__ cnt_int,
          const float* __restrict__ node_feat, const int* __restrict__ center_idx,
          float* __restrict__ out, int nc) {
    int c = blockIdx.x;
    if (c >= nc) return;
    int lane = threadIdx.x;
    int n = cnt_int[c];
    int nl = n > CAP ? CAP : n;
    if (lane < MDIM) {
        const int* bk = bucket + (size_t)c * CAP;
        float acc = 0.f;
        int s = 0;
        for (; s + 4 <= nl; s += 4) {
            int e0 = bk[s], e1 = bk[s + 1], e2 = bk[s + 2], e3 = bk[s + 3];
            float a0 = bf2f(edge_m[(size_t)e0 * MDIM + lane]);
            float a1 = bf2f(edge_m[(size_t)e1 * MDIM + lane]);
            float a2 = bf2f(edge_m[(size_t)e2 * MDIM + lane]);
            float a3 = bf2f(edge_m[(size_t)e3 * MDIM + lane]);
            acc += (a0 + a1) + (a2 + a3);
        }
        for (; s < nl; ++s) acc += bf2f(edge_m[(size_t)bk[s] * MDIM + lane]);
        float agg = acc / fmaxf((float)n, 1.f);
        if (lane < NA) out[(size_t)c * 64 + S0 + lane] = agg;
        else out[(size_t)nc * 64 + (size_t)c * 48 + (lane - NA)] = agg;
    } else if (lane < MDIM + S0) {
        int t = lane - MDIM;
        out[(size_t)c * 64 + t] = node_feat[(size_t)center_idx[c] * S0 + t];
    }
}

extern "C" void kernel_launch(void* const* d_in, const int* in_sizes, int n_in,
                              void* d_out, int out_size, void* d_ws, size_t ws_size,
                              hipStream_t stream) {
    const float* pos        = (const float*)d_in[0];
    const float* elem_id    = (const float*)d_in[1];
    const float* charge     = (const float*)d_in[2];
    const int*   center_idx = (const int*)d_in[3];
    const int*   edge_center= (const int*)d_in[4];
    const int*   edge_env   = (const int*)d_in[5];
    const float* emb        = (const float*)d_in[6];
    const float* Wfeat      = (const float*)d_in[7];
    const float* Ws         = (const float*)d_in[8];
    const float* Wv         = (const float*)d_in[9];

    int nN = in_sizes[0] / 3;
    int nC = in_sizes[3];
    int nE = in_sizes[4];

    char* wsb = (char*)d_ws;
    size_t off = 0;
    auto alloc = [&](size_t bytes) { char* p = wsb + off; off = (off + bytes + 15) & ~(size_t)15; return p; };
    uint4* edge_m    = (uint4*)alloc((size_t)nE * MDIM * 2);
    float* node_feat = (float*)alloc((size_t)nN * S0 * 4);
    int*   bucket    = (int*)alloc((size_t)nC * CAP * 4);
    int*   cnt_int   = (int*)alloc((size_t)nC * 4);
    float* WsT       = (float*)alloc(NRBF * 48 * S0 * 4);
    float* WvT       = (float*)alloc(NB * S0 * 4);
    int*   bine      = (int*)alloc((size_t)nE * 4);
    int*   bin_edges = (int*)alloc(((size_t)nE + NBIN * 256 + 256) * 4);
    int*   bin_cnt   = (int*)alloc(NBIN * 4);
    int*   cursor    = (int*)alloc(NBIN * 4);
    int*   pad_base  = (int*)alloc((NBIN + 1) * 4);

    hipMemsetAsync(cnt_int, 0, (size_t)nC * 4, stream);
    hipMemsetAsync(bin_cnt, 0, NBIN * 4, stream);
    hipMemsetAsync(cursor, 0, NBIN * 4, stream);
    hipMemsetAsync(bin_edges, 0xFF, ((size_t)nE + NBIN * 256 + 256) * 4, stream);

    k_prep<<<(NRBF * 48 * S0 + 255) / 256, 256, 0, stream>>>(Ws, Wv, WsT, WvT);
    k_node_feat<<<(nN + 63) / 64, 256, 0, stream>>>(elem_id, charge, emb, Wfeat, node_feat, nN);
    k_fill2<<<(nE + 255) / 256, 256, 0, stream>>>(pos, center_idx, edge_center, edge_env,
                                                  cnt_int, bucket, bine, bin_cnt, nE);
    k_prefix<<<1, 32, 0, stream>>>(bin_cnt, pad_base);
    k_scatter<<<(nE + 255) / 256, 256, 0, stream>>>(bine, pad_base, cursor, bin_edges, nE);
    k_edges_b<<<(nE + 255) / 256 + NBIN, 256, 0, stream>>>(pos, center_idx, edge_center, edge_env,
                                                           WsT, WvT, node_feat, bin_edges, pad_base, edge_m);
    k_centers<<<nC, 128, 0, stream>>>((const unsigned short*)edge_m, bucket, cnt_int,
                                      node_feat, center_idx, (float*)d_out, nC);
}

// Round 15
// 319.660 us; speedup vs baseline: 8.3348x; 8.3348x over previous
//
#include <hip/hip_runtime.h>
#include <math.h>

#define S0 32
#define NRBF 16
#define NA 32
#define NB 16
#define MDIM 80            // NA + 3*NB
#define NELEM 118
#define CAP 96             // bucket capacity per center
#define NBIN 18            // m0 bins 0..17 (17 = "both channels zero")
#define CH 2048            // edges per chunk for the deterministic scatter

__device__ inline unsigned short f2bf(float a) {
    unsigned u = __float_as_uint(a);
    return (unsigned short)((u + 0x7fffu + ((u >> 16) & 1u)) >> 16);
}
__device__ inline unsigned pack_bf2(float a, float b) {
    return (unsigned)f2bf(a) | ((unsigned)f2bf(b) << 16);
}
__device__ inline float bf2f(unsigned short u) {
    return __uint_as_float(((unsigned)u) << 16);
}

// ---------------- Kernel 0: weight transpose (fp32, for scalar-broadcast reads) ----------------
__global__ void k_prep(const float* __restrict__ Ws, const float* __restrict__ Wv,
                       float* __restrict__ WsT, float* __restrict__ WvT) {
    int t = blockIdx.x * 256 + threadIdx.x;
    if (t < NRBF * 48 * S0) {          // WsT[j][k][i] = Ws[i][j][k]
        int j = t / (48 * S0);
        int r = t - j * (48 * S0);
        int k = r / S0;
        int i = r - k * S0;
        WsT[t] = Ws[(i * NRBF + j) * 48 + k];
    }
    if (t < NB * S0) {                 // WvT[k][i] = Wv[i][k]
        int k = t / S0, i = t - k * S0;
        WvT[t] = Wv[i * NB + k];
    }
}

// ---------------- Kernel 1: node features ----------------
__global__ void __launch_bounds__(256)
k_node_feat(const float* __restrict__ elem_id,
            const float* __restrict__ charge,
            const float* __restrict__ emb,
            const float* __restrict__ Wfeat,
            float* __restrict__ node_feat, int n) {
    __shared__ float rows[64 * 121];
    __shared__ float WfL[11 * S0];
    int tid = threadIdx.x;
    int blockBase = blockIdx.x * 64;
    int nRows = n - blockBase; if (nRows > 64) nRows = 64;
    if (nRows <= 0) return;
    int totF = nRows * NELEM;
    const float* src = elem_id + (size_t)blockBase * NELEM;
    for (int t = tid; t < totF; t += 256) {
        int r = t / NELEM, c = t - r * NELEM;
        rows[r * 121 + c] = src[t];
    }
    for (int t = tid; t < 11 * S0; t += 256) WfL[t] = Wfeat[t];
    __syncthreads();
    if (tid >= nRows) return;
    int i = blockBase + tid;
    const float* myrow = rows + tid * 121;
    float best = -1e30f; int bi = 0;
    for (int c = 0; c < NELEM; ++c) {
        float v = myrow[c];
        if (v > best) { best = v; bi = c; }
    }
    float ns[11];
#pragma unroll
    for (int c = 0; c < 10; ++c) ns[c] = emb[bi * 10 + c];
    ns[10] = charge[i];
    float out[S0];
#pragma unroll
    for (int k = 0; k < S0; ++k) out[k] = 0.f;
#pragma unroll
    for (int c = 0; c < 11; ++c) {
        float f = ns[c];
#pragma unroll
        for (int k = 0; k < S0; ++k) out[k] = fmaf(f, WfL[c * S0 + k], out[k]);
    }
    float4* o = (float4*)(node_feat + (size_t)i * S0);
#pragma unroll
    for (int q = 0; q < S0 / 4; ++q)
        o[q] = make_float4(out[4 * q], out[4 * q + 1], out[4 * q + 2], out[4 * q + 3]);
}

// ---------------- Kernel 2: bucket fill + per-edge bin id (NO hot atomics) ----------------
__global__ void k_fill(const float* __restrict__ pos, const int* __restrict__ center_idx,
                       const int* __restrict__ edge_center, const int* __restrict__ edge_env,
                       int* __restrict__ cnt_int, int* __restrict__ bucket,
                       int* __restrict__ bine, int nE) {
    int e = blockIdx.x * blockDim.x + threadIdx.x;
    if (e >= nE) return;
    int ec = edge_center[e];
    int en = edge_env[e];
    int gc = center_idx[ec];
    float px = pos[3 * (size_t)gc + 0] - pos[3 * (size_t)en + 0];
    float py = pos[3 * (size_t)gc + 1] - pos[3 * (size_t)en + 1];
    float pz = pos[3 * (size_t)gc + 2] - pos[3 * (size_t)en + 2];
    float d = sqrtf(px * px + py * py + pz * pz) + 1e-8f;
    const float inv_step = 3.4f;  // (NRBF+1)/5
    float u = d * inv_step;
    int m0 = (int)floorf(u);
    if (m0 > 17) m0 = 17;
    bine[e] = m0;
    int slot = atomicAdd(&cnt_int[ec], 1);   // 10k addresses, ~32/address: cheap
    if (slot < CAP) bucket[(size_t)ec * CAP + slot] = e;
}

// ---------------- Kernel 3: per-chunk bin histogram (LDS only, plain stores) ----------------
__global__ void __launch_bounds__(256)
k_hist(const int* __restrict__ bine, int* __restrict__ chunk_cnt, int nE) {
    __shared__ int hist[NBIN];
    int chunk = blockIdx.x;
    int tid = threadIdx.x;
    if (tid < NBIN) hist[tid] = 0;
    __syncthreads();
    int base = chunk * CH;
#pragma unroll
    for (int r = 0; r < CH / 256; ++r) {
        int e = base + r * 256 + tid;
        if (e < nE) atomicAdd(&hist[bine[e]], 1);   // LDS atomic
    }
    __syncthreads();
    if (tid < NBIN) chunk_cnt[chunk * NBIN + tid] = hist[tid];
}

// ---------------- Kernel 4: scan chunk counts -> per-chunk bases + padded bin bases ----------------
__global__ void k_prefix2(const int* __restrict__ chunk_cnt, int* __restrict__ chunk_base,
                          int* __restrict__ pad_base, int nchunk) {
    __shared__ int tot[NBIN];
    int t = threadIdx.x;
    if (t < NBIN) {
        int acc = 0;
        for (int c = 0; c < nchunk; ++c) acc += chunk_cnt[c * NBIN + t];
        tot[t] = acc;
    }
    __syncthreads();
    __shared__ int pb[NBIN + 1];
    if (t == 0) {
        int acc = 0;
        for (int b = 0; b < NBIN; ++b) {
            pb[b] = acc;
            pad_base[b] = acc;
            acc += ((tot[b] + 255) / 256) * 256;   // pad each bin to x256
        }
        pb[NBIN] = acc;
        pad_base[NBIN] = acc;
    }
    __syncthreads();
    if (t < NBIN) {
        int acc = pb[t];
        for (int c = 0; c < nchunk; ++c) {
            chunk_base[c * NBIN + t] = acc;
            acc += chunk_cnt[c * NBIN + t];
        }
    }
}

// ---------------- Kernel 5: deterministic scatter (LDS atomics only) ----------------
__global__ void __launch_bounds__(256)
k_scatter2(const int* __restrict__ bine, const int* __restrict__ chunk_base,
           int* __restrict__ bin_edges, int nE) {
    __shared__ int hist[NBIN];
    __shared__ int lbase[NBIN];
    int chunk = blockIdx.x;
    int tid = threadIdx.x;
    if (tid < NBIN) { hist[tid] = 0; lbase[tid] = chunk_base[chunk * NBIN + tid]; }
    __syncthreads();
    int base = chunk * CH;
#pragma unroll
    for (int r = 0; r < CH / 256; ++r) {
        int e = base + r * 256 + tid;
        if (e < nE) {
            int b = bine[e];
            int ls = atomicAdd(&hist[b], 1);      // LDS atomic
            bin_edges[lbase[b] + ls] = e;
        }
    }
}

// ---------------- Kernel 6: binned per-edge tensor product (wave-uniform weights) ----------------
__global__ void __launch_bounds__(256)
k_edges_b(const float* __restrict__ pos, const int* __restrict__ center_idx,
          const int* __restrict__ edge_center, const int* __restrict__ edge_env,
          const float* __restrict__ WsT,   // [j][k][i] fp32
          const float* __restrict__ WvT,   // [k][i] fp32
          const float* __restrict__ node_feat,
          const int* __restrict__ bin_edges, const int* __restrict__ pad_base,
          uint4* __restrict__ edge_m) {
    __shared__ int pbS[NBIN + 1];
    if (threadIdx.x <= NBIN) pbS[threadIdx.x] = pad_base[threadIdx.x];
    __syncthreads();
    int slotBase = blockIdx.x * 256;
    int total = pbS[NBIN];
    if (slotBase >= total) return;
    int b = 0;
    while (b < NBIN - 1 && slotBase >= pbS[b + 1]) ++b;   // block lies in ONE bin (padded)
    b = __builtin_amdgcn_readfirstlane(b);

    int slot = slotBase + threadIdx.x;
    int e = (slot < total) ? bin_edges[slot] : -1;
    bool valid = e >= 0;
    int ei = valid ? e : 0;

    int ec = edge_center[ei];
    int en = edge_env[ei];
    int gc = center_idx[ec];
    float px = pos[3 * (size_t)gc + 0] - pos[3 * (size_t)en + 0];
    float py = pos[3 * (size_t)gc + 1] - pos[3 * (size_t)en + 1];
    float pz = pos[3 * (size_t)gc + 2] - pos[3 * (size_t)en + 2];
    float d = sqrtf(px * px + py * py + pz * pz) + 1e-8f;

    const float inv_step = 3.4f;
    float u = d * inv_step;
    float f0 = u - (float)b;            // exact: b == floor(u) for b<=16
    float t0 = 0.5f * (float)M_PI * f0;
    float r0 = (b >= 1 && b <= 16) ? cosf(t0) : 0.f;   // channel j0 = b-1
    float r1 = (b <= 15) ? sinf(t0) : 0.f;             // channel j1 = b
    if (!valid) { r0 = 0.f; r1 = 0.f; }
    int j0 = b - 1; if (j0 < 0) j0 = 0; if (j0 > 15) j0 = 15;
    int j1 = b;     if (j1 > 15) j1 = 15;
    const float* w0 = WsT + j0 * (48 * S0);   // wave-uniform row pointers -> s_load
    const float* w1 = WsT + j1 * (48 * S0);

    float h[S0];
    {
        const float4* hp = (const float4*)(node_feat + (size_t)en * S0);
#pragma unroll
        for (int q = 0; q < S0 / 4; ++q) {
            float4 t = hp[q];
            h[4 * q + 0] = t.x; h[4 * q + 1] = t.y; h[4 * q + 2] = t.z; h[4 * q + 3] = t.w;
        }
    }

    float acc[48];
#pragma unroll 2
    for (int k = 0; k < 48; ++k) {
        float a0 = 0.f, a1 = 0.f;
        const float* w0k = w0 + k * S0;
        const float* w1k = w1 + k * S0;
#pragma unroll
        for (int i = 0; i < S0; ++i) {
            a0 = fmaf(h[i], w0k[i], a0);
            a1 = fmaf(h[i], w1k[i], a1);
        }
        acc[k] = fmaf(r0, a0, r1 * a1);
    }

    float hv[NB];
#pragma unroll 2
    for (int k = 0; k < NB; ++k) {
        float a = 0.f;
        const float* wk = WvT + k * S0;
#pragma unroll
        for (int i = 0; i < S0; ++i) a = fmaf(h[i], wk[i], a);
        hv[k] = a;
    }

    const float inv_s = 0.04419417382415922f;  // 1/sqrt(512)
    const float inv_v = 0.17677669529663687f;  // 1/sqrt(32)
    float m[MDIM];
#pragma unroll
    for (int k = 0; k < NA; ++k) {
        float s = acc[k] * inv_s;
        float sg = 1.f / (1.f + expf(-s));
        m[k] = s * sg;
    }
    float ys = 1.7320508075688772f / d;
    float Yx = ys * px, Yy = ys * py, Yz = ys * pz;
#pragma unroll
    for (int k = 0; k < NB; ++k) {
        float s = acc[NA + k] * inv_s;
        float g = 1.f / (1.f + expf(-s));
        float vv = hv[k] * inv_v * g;
        m[NA + 3 * k + 0] = vv * Yx;
        m[NA + 3 * k + 1] = vv * Yy;
        m[NA + 3 * k + 2] = vv * Yz;
    }

    if (valid) {
        uint4* dst = edge_m + (size_t)ei * 10;
#pragma unroll
        for (int q = 0; q < 10; ++q) {
            uint4 w;
            w.x = pack_bf2(m[8 * q + 0], m[8 * q + 1]);
            w.y = pack_bf2(m[8 * q + 2], m[8 * q + 3]);
            w.z = pack_bf2(m[8 * q + 4], m[8 * q + 5]);
            w.w = pack_bf2(m[8 * q + 6], m[8 * q + 7]);
            dst[q] = w;
        }
    }
}

// ---------------- Kernel 7: per-center reduce + finalize ----------------
__global__ void __launch_bounds__(128)
k_centers(const unsigned short* __restrict__ edge_m,
          const int* __restrict__ bucket, const int* __restrict__ cnt_int,
          const float* __restrict__ node_feat, const int* __restrict__ center_idx,
          float* __restrict__ out, int nc) {
    int c = blockIdx.x;
    if (c >= nc) return;
    int lane = threadIdx.x;
    int n = cnt_int[c];
    int nl = n > CAP ? CAP : n;
    if (lane < MDIM) {
        const int* bk = bucket + (size_t)c * CAP;
        float acc = 0.f;
        int s = 0;
        for (; s + 4 <= nl; s += 4) {
            int e0 = bk[s], e1 = bk[s + 1], e2 = bk[s + 2], e3 = bk[s + 3];
            float a0 = bf2f(edge_m[(size_t)e0 * MDIM + lane]);
            float a1 = bf2f(edge_m[(size_t)e1 * MDIM + lane]);
            float a2 = bf2f(edge_m[(size_t)e2 * MDIM + lane]);
            float a3 = bf2f(edge_m[(size_t)e3 * MDIM + lane]);
            acc += (a0 + a1) + (a2 + a3);
        }
        for (; s < nl; ++s) acc += bf2f(edge_m[(size_t)bk[s] * MDIM + lane]);
        float agg = acc / fmaxf((float)n, 1.f);
        if (lane < NA) out[(size_t)c * 64 + S0 + lane] = agg;
        else out[(size_t)nc * 64 + (size_t)c * 48 + (lane - NA)] = agg;
    } else if (lane < MDIM + S0) {
        int t = lane - MDIM;
        out[(size_t)c * 64 + t] = node_feat[(size_t)center_idx[c] * S0 + t];
    }
}

extern "C" void kernel_launch(void* const* d_in, const int* in_sizes, int n_in,
                              void* d_out, int out_size, void* d_ws, size_t ws_size,
                              hipStream_t stream) {
    const float* pos        = (const float*)d_in[0];
    const float* elem_id    = (const float*)d_in[1];
    const float* charge     = (const float*)d_in[2];
    const int*   center_idx = (const int*)d_in[3];
    const int*   edge_center= (const int*)d_in[4];
    const int*   edge_env   = (const int*)d_in[5];
    const float* emb        = (const float*)d_in[6];
    const float* Wfeat      = (const float*)d_in[7];
    const float* Ws         = (const float*)d_in[8];
    const float* Wv         = (const float*)d_in[9];

    int nN = in_sizes[0] / 3;
    int nC = in_sizes[3];
    int nE = in_sizes[4];
    int nchunk = (nE + CH - 1) / CH;

    char* wsb = (char*)d_ws;
    size_t off = 0;
    auto alloc = [&](size_t bytes) { char* p = wsb + off; off = (off + bytes + 15) & ~(size_t)15; return p; };
    uint4* edge_m    = (uint4*)alloc((size_t)nE * MDIM * 2);
    float* node_feat = (float*)alloc((size_t)nN * S0 * 4);
    int*   bucket    = (int*)alloc((size_t)nC * CAP * 4);
    int*   cnt_int   = (int*)alloc((size_t)nC * 4);
    float* WsT       = (float*)alloc(NRBF * 48 * S0 * 4);
    float* WvT       = (float*)alloc(NB * S0 * 4);
    int*   bine      = (int*)alloc((size_t)nE * 4);
    int*   bin_edges = (int*)alloc(((size_t)nE + NBIN * 256 + 256) * 4);
    int*   chunk_cnt = (int*)alloc((size_t)nchunk * NBIN * 4);
    int*   chunk_base= (int*)alloc((size_t)nchunk * NBIN * 4);
    int*   pad_base  = (int*)alloc((NBIN + 1) * 4);

    hipMemsetAsync(cnt_int, 0, (size_t)nC * 4, stream);
    hipMemsetAsync(bin_edges, 0xFF, ((size_t)nE + NBIN * 256 + 256) * 4, stream);

    k_prep<<<(NRBF * 48 * S0 + 255) / 256, 256, 0, stream>>>(Ws, Wv, WsT, WvT);
    k_node_feat<<<(nN + 63) / 64, 256, 0, stream>>>(elem_id, charge, emb, Wfeat, node_feat, nN);
    k_fill<<<(nE + 255) / 256, 256, 0, stream>>>(pos, center_idx, edge_center, edge_env,
                                                 cnt_int, bucket, bine, nE);
    k_hist<<<nchunk, 256, 0, stream>>>(bine, chunk_cnt, nE);
    k_prefix2<<<1, 32, 0, stream>>>(chunk_cnt, chunk_base, pad_base, nchunk);
    k_scatter2<<<nchunk, 256, 0, stream>>>(bine, chunk_base, bin_edges, nE);
    k_edges_b<<<(nE + 255) / 256 + NBIN, 256, 0, stream>>>(pos, center_idx, edge_center, edge_env,
                                                           WsT, WvT, node_feat, bin_edges, pad_base, edge_m);
    k_centers<<<nC, 128, 0, stream>>>((const unsigned short*)edge_m, bucket, cnt_int,
                                      node_feat, center_idx, (float*)d_out, nC);
}